// Round 1
// baseline (385.546 us; speedup 1.0000x reference)
//
#include <hip/hip_runtime.h>
#include <math.h>

#define NDEG 64          // N
#define LMAX 66          // N + 2 (table dimension)
#define LDCB 67          // cBar/sBar row stride (N + 3)

#define MU_F   398600441800000.0f
#define AREF_F 6378136.3f

// ---------------------------------------------------------------------------
// Setup kernel: build n1[l][m], n2[l][m] (LMAX x LMAX, stride LMAX) and
// diag[l], sub[l] into workspace. Runs every launch (ws is re-poisoned).
// Computed in double to match the numpy-fp64-then-cast reference constants.
// ---------------------------------------------------------------------------
__global__ void pines_setup_tables(float* __restrict__ n1,
                                   float* __restrict__ n2,
                                   float* __restrict__ diag,
                                   float* __restrict__ sub) {
    int tid = blockIdx.x * blockDim.x + threadIdx.x;
    if (tid == 0) {
        // diag = cumprod(f), sub — sequential over l (66 iters, trivial)
        diag[0] = 1.0f;
        sub[0]  = 0.0f;
        double d = 1.0;
        double kprev = 1.0;                 // k[0] = 1
        for (int l = 1; l < LMAX; ++l) {
            double k = 2.0;                 // k[l>=1] = 2
            double f = sqrt((2.0 * l + 1.0) * k / (2.0 * l * kprev));
            d *= f;
            diag[l] = (float)d;
            sub[l]  = (float)sqrt(2.0 * l * kprev / k);
            kprev = k;
        }
    }
    int total = LMAX * LMAX;
    int stride = blockDim.x * gridDim.x;
    for (int i = tid; i < total; i += stride) {
        int l = i / LMAX;
        int m = i % LMAX;
        float v1 = 0.0f, v2 = 0.0f;
        if (l >= m + 2) {
            double dl = (double)l, dm = (double)m;
            double d1 = (dl - dm) * (dl + dm);
            v1 = (float)sqrt((2.0 * dl + 1.0) * (2.0 * dl - 1.0) / d1);
            double d2   = (dl + dm) * (dl - dm) * (2.0 * dl - 3.0);
            double num2 = (dl + dm - 1.0) * (2.0 * dl + 1.0) * (dl - dm - 1.0);
            v2 = (float)sqrt(num2 / d2);
        }
        n1[i] = v1;
        n2[i] = v2;
    }
}

// ---------------------------------------------------------------------------
// Main kernel: one thread per batch element. Column-major (fixed m, recurse
// over l) Pines recursion: aBar[m][m] = diag[m], aBar[m+1][m] =
// sub[m+1]*diag[m+1]*u, aBar[l][m] = u*n1[l][m]*aBar[l-1][m] -
// n2[l][m]*aBar[l-2][m]. Contribution per (l,m), l in [1,N]:
//   rhol[l] * aBar[l][m] * (cBar[l][m]*Re((s+it)^m) + sBar[l][m]*Im((s+it)^m))
// l=0 term is exactly MU/r. Table reads are wave-uniform -> scalar loads.
// ---------------------------------------------------------------------------
__global__ __launch_bounds__(256) void pines_kernel(
        const float4* __restrict__ inputs,
        const float*  __restrict__ cBar,
        const float*  __restrict__ sBar,
        const float*  __restrict__ n1,
        const float*  __restrict__ n2,
        const float*  __restrict__ diag,
        const float*  __restrict__ sub,
        float* __restrict__ out, int B) {
    int idx = blockIdx.x * blockDim.x + threadIdx.x;
    int lidx = idx < B ? idx : (B - 1);       // uniform control flow

    float4 in = inputs[lidx];
    float r = in.x, s = in.y, t = in.z, u = in.w;

    float rho  = AREF_F / r;
    float mu_r = MU_F / r;

    float sum = mu_r;                          // l = 0 term
    float re = 1.0f, im = 0.0f;                // (s + i t)^m
    float rho_m = mu_r;                        // mu_r * rho^m

    for (int m = 0; m <= NDEG; ++m) {
        float p0 = diag[m];                    // aBar[m][m]
        float rl = rho_m;                      // mu_r * rho^l at l = m
        if (m >= 1) {
            float cs = cBar[m * LDCB + m] * re + sBar[m * LDCB + m] * im;
            sum += rl * p0 * cs;
        }
        if (m < NDEG) {
            float p1 = sub[m + 1] * diag[m + 1] * u;   // aBar[m+1][m]
            rl *= rho;
            float cs = cBar[(m + 1) * LDCB + m] * re + sBar[(m + 1) * LDCB + m] * im;
            sum += rl * p1 * cs;
            for (int l = m + 2; l <= NDEG; ++l) {
                float p = u * (n1[l * LMAX + m] * p1) - n2[l * LMAX + m] * p0;
                rl *= rho;
                float cs2 = cBar[l * LDCB + m] * re + sBar[l * LDCB + m] * im;
                sum += rl * p * cs2;
                p0 = p1;
                p1 = p;
            }
        }
        // advance (s + i t)^m
        float nre = s * re - t * im;
        float nim = s * im + t * re;
        re = nre;
        im = nim;
        rho_m *= rho;
    }

    if (idx < B) out[idx] = -sum;
}

extern "C" void kernel_launch(void* const* d_in, const int* in_sizes, int n_in,
                              void* d_out, int out_size, void* d_ws, size_t ws_size,
                              hipStream_t stream) {
    const float* inputs = (const float*)d_in[0];   // (B, 4)
    const float* cBar   = (const float*)d_in[1];   // (67, 67)
    const float* sBar   = (const float*)d_in[2];   // (67, 67)
    float* out = (float*)d_out;
    int B = in_sizes[0] / 4;

    float* n1   = (float*)d_ws;
    float* n2   = n1 + LMAX * LMAX;
    float* diag = n2 + LMAX * LMAX;
    float* sub  = diag + LMAX;

    hipLaunchKernelGGL(pines_setup_tables, dim3(32), dim3(256), 0, stream,
                       n1, n2, diag, sub);

    int blocks = (B + 255) / 256;
    hipLaunchKernelGGL(pines_kernel, dim3(blocks), dim3(256), 0, stream,
                       (const float4*)inputs, cBar, sBar, n1, n2, diag, sub,
                       out, B);
}

// Round 2
// 150.566 us; speedup vs baseline: 2.5606x; 2.5606x over previous
//
#include <hip/hip_runtime.h>
#include <math.h>

#define NDEG 64          // N
#define LMAX 66          // N + 2 (table dimension)
#define LDCB 67          // cBar/sBar row stride (N + 3)

#define MU_F   398600441800000.0f
#define AREF_F 6378136.3f

#define NSUB 8           // sub-threads per element
#define EPB  32          // elements per block (block = NSUB*EPB = 256)

// ---------------------------------------------------------------------------
// Setup kernel: build n1[l][m], n2[l][m] (LMAX x LMAX, stride LMAX) and
// diag[l], sub[l] into workspace. Runs every launch (ws is re-poisoned).
// ---------------------------------------------------------------------------
__global__ void pines_setup_tables(float* __restrict__ n1,
                                   float* __restrict__ n2,
                                   float* __restrict__ diag,
                                   float* __restrict__ sub) {
    int tid = blockIdx.x * blockDim.x + threadIdx.x;
    if (tid == 0) {
        diag[0] = 1.0f;
        sub[0]  = 0.0f;
        double d = 1.0;
        double kprev = 1.0;                 // k[0] = 1
        for (int l = 1; l < LMAX; ++l) {
            double k = 2.0;                 // k[l>=1] = 2
            double f = sqrt((2.0 * l + 1.0) * k / (2.0 * l * kprev));
            d *= f;
            diag[l] = (float)d;
            sub[l]  = (float)sqrt(2.0 * l * kprev / k);
            kprev = k;
        }
    }
    int total = LMAX * LMAX;
    int stride = blockDim.x * gridDim.x;
    for (int i = tid; i < total; i += stride) {
        int l = i / LMAX;
        int m = i % LMAX;
        float v1 = 0.0f, v2 = 0.0f;
        if (l >= m + 2) {
            double dl = (double)l, dm = (double)m;
            double d1 = (dl - dm) * (dl + dm);
            v1 = (float)sqrt((2.0 * dl + 1.0) * (2.0 * dl - 1.0) / d1);
            double d2   = (dl + dm) * (dl - dm) * (2.0 * dl - 3.0);
            double num2 = (dl + dm - 1.0) * (2.0 * dl + 1.0) * (dl - dm - 1.0);
            v2 = (float)sqrt(num2 / d2);
        }
        n1[i] = v1;
        n2[i] = v2;
    }
}

// ---------------------------------------------------------------------------
// Main kernel: NSUB=8 threads cooperate on one element. Sub j owns columns
// m = j, 15-j, 16+j, 31-j, 32+j, 47-j, 48+j, 63-j  (zigzag: every sub gets
// exactly 268 inner iterations). Sub 0 additionally picks up the m=64
// diagonal term (its zigzag walk lands on m=64 after the last column).
// Column-start powers (s+it)^m and mu/r*rho^m are maintained with two
// precomputed step powers (deltas alternate d1=15-2j, d2=1+2j).
// Thread layout: t = j*EPB + e  (sub is SLOW) so a 64-lane wave holds only
// 2 distinct m-sequences -> table loads touch <=2 cache lines.
// ---------------------------------------------------------------------------
__global__ __launch_bounds__(256) void pines_kernel(
        const float4* __restrict__ inputs,
        const float*  __restrict__ cBar,
        const float*  __restrict__ sBar,
        const float*  __restrict__ n1,
        const float*  __restrict__ n2,
        const float*  __restrict__ diag,
        const float*  __restrict__ sub,
        float* __restrict__ out, int B) {
    __shared__ float part[NSUB][EPB];

    int t = threadIdx.x;
    int j = t >> 5;                 // sub index 0..7
    int e = t & (EPB - 1);          // element-in-block
    int elem = blockIdx.x * EPB + e;
    int lelem = elem < B ? elem : (B - 1);

    float4 in = inputs[lelem];
    float r = in.x, ss = in.y, tt = in.z, u = in.w;

    float rho  = AREF_F / r;
    float mu_r = MU_F / r;

    int d1 = 15 - 2 * j;
    int d2 = 1 + 2 * j;

    // (s+it)^e_ via square-and-multiply (e_ <= 15)
    auto cpow = [&](int e_, float& re_, float& im_) {
        float br = ss, bi = tt;
        re_ = 1.0f; im_ = 0.0f;
        int ee = e_;
        while (ee) {
            if (ee & 1) {
                float nr = re_ * br - im_ * bi;
                im_ = re_ * bi + im_ * br;
                re_ = nr;
            }
            float sr = br * br - bi * bi;
            bi = 2.0f * br * bi;
            br = sr;
            ee >>= 1;
        }
    };
    auto rpow = [&](int e_) {
        float b = rho, acc = 1.0f;
        int ee = e_;
        while (ee) {
            if (ee & 1) acc *= b;
            b *= b;
            ee >>= 1;
        }
        return acc;
    };

    float re, im;      cpow(j, re, im);
    float s1r, s1i;    cpow(d1, s1r, s1i);
    float s2r, s2i;    cpow(d2, s2r, s2i);
    float rstep1 = rpow(d1);
    float rstep2 = rpow(d2);
    float rho_m  = mu_r * rpow(j);       // mu/r * rho^m at m = j

    float sum = (j == 0) ? mu_r : 0.0f;  // l = 0 term, added once

    int m = j;
    #pragma unroll 1
    for (int k = 0; k < 8; ++k) {
        float p0 = diag[m];              // aBar[m][m]
        float rl = rho_m;
        if (m >= 1) {
            float cs = cBar[m * LDCB + m] * re + sBar[m * LDCB + m] * im;
            sum += rl * p0 * cs;
        }
        if (m < NDEG) {
            float p1 = sub[m + 1] * diag[m + 1] * u;   // aBar[m+1][m]
            rl *= rho;
            float cs = cBar[(m + 1) * LDCB + m] * re + sBar[(m + 1) * LDCB + m] * im;
            sum += rl * p1 * cs;
            for (int l = m + 2; l <= NDEG; ++l) {
                float p = u * (n1[l * LMAX + m] * p1) - n2[l * LMAX + m] * p0;
                rl *= rho;
                float cs2 = cBar[l * LDCB + m] * re + sBar[l * LDCB + m] * im;
                sum += rl * p * cs2;
                p0 = p1;
                p1 = p;
            }
        }
        // advance zigzag: even k -> +d1, odd k -> +d2
        if (k & 1) {
            float nr = re * s2r - im * s2i;
            im = re * s2i + im * s2r; re = nr;
            rho_m *= rstep2; m += d2;
        } else {
            float nr = re * s1r - im * s1i;
            im = re * s1i + im * s1r; re = nr;
            rho_m *= rstep1; m += d1;
        }
    }
    // sub 0's walk ends at m = 63 + d2 = 64: add the m=64 diagonal term
    if (j == 0) {
        float cs = cBar[64 * LDCB + 64] * re + sBar[64 * LDCB + 64] * im;
        sum += rho_m * diag[64] * cs;
    }

    part[j][e] = sum;
    __syncthreads();
    if (j == 0) {
        float tot = 0.0f;
        #pragma unroll
        for (int q = 0; q < NSUB; ++q) tot += part[q][e];
        if (elem < B) out[elem] = -tot;
    }
}

extern "C" void kernel_launch(void* const* d_in, const int* in_sizes, int n_in,
                              void* d_out, int out_size, void* d_ws, size_t ws_size,
                              hipStream_t stream) {
    const float* inputs = (const float*)d_in[0];   // (B, 4)
    const float* cBar   = (const float*)d_in[1];   // (67, 67)
    const float* sBar   = (const float*)d_in[2];   // (67, 67)
    float* out = (float*)d_out;
    int B = in_sizes[0] / 4;

    float* n1   = (float*)d_ws;
    float* n2   = n1 + LMAX * LMAX;
    float* diag = n2 + LMAX * LMAX;
    float* sub  = diag + LMAX;

    hipLaunchKernelGGL(pines_setup_tables, dim3(32), dim3(256), 0, stream,
                       n1, n2, diag, sub);

    int blocks = (B + EPB - 1) / EPB;
    hipLaunchKernelGGL(pines_kernel, dim3(blocks), dim3(256), 0, stream,
                       (const float4*)inputs, cBar, sBar, n1, n2, diag, sub,
                       out, B);
}

// Round 3
// 139.276 us; speedup vs baseline: 2.7682x; 1.0811x over previous
//
#include <hip/hip_runtime.h>
#include <math.h>

#define NDEG 64          // N
#define LMAX 66          // N + 2 (constant-table dimension)
#define LDCB 67          // cBar/sBar row stride (N + 3)
#define TABW 66          // tab row width (per m: l entries, l-contiguous)

#define MU_F   398600441800000.0f
#define AREF_F 6378136.3f

#define NSUB 8           // sub-threads per element
#define EPB  32          // elements per block (block = NSUB*EPB = 256)

// ---------------------------------------------------------------------------
// Setup (1 block): pack per-(l,m) constants into ONE float4 table
//   tab[m*TABW + l] = (n1[l][m], n2[l][m], cBar[l][m], sBar[l][m]),  l>=m+2
// plus column-head tables:
//   headA[m] = (diag[m], sub[m+1]*diag[m+1], cBar[m][m], sBar[m][m])
//   headB[m] = (cBar[m+1][m], sBar[m+1][m], 0, 0)
// ---------------------------------------------------------------------------
__global__ void pines_setup(const float* __restrict__ cBar,
                            const float* __restrict__ sBar,
                            float4* __restrict__ tab,
                            float4* __restrict__ headA,
                            float4* __restrict__ headB) {
    __shared__ double sh_diag[LMAX], sh_sub[LMAX];
    int t = threadIdx.x;
    if (t == 0) {
        sh_diag[0] = 1.0; sh_sub[0] = 0.0;
        double d = 1.0, kprev = 1.0;            // k[0]=1, k[l>=1]=2
        for (int l = 1; l < LMAX; ++l) {
            double k = 2.0;
            double f = sqrt((2.0 * l + 1.0) * k / (2.0 * l * kprev));
            d *= f;
            sh_diag[l] = d;
            sh_sub[l]  = sqrt(2.0 * l * kprev / k);
            kprev = k;
        }
    }
    __syncthreads();
    for (int m = t; m <= NDEG; m += blockDim.x) {
        float dg = (float)sh_diag[m];
        float sd = (float)(sh_sub[m + 1] * sh_diag[m + 1]);   // m+1 <= 65 ok
        headA[m] = make_float4(dg, sd, cBar[m * LDCB + m], sBar[m * LDCB + m]);
        float cb1 = (m < NDEG) ? cBar[(m + 1) * LDCB + m] : 0.0f;
        float sb1 = (m < NDEG) ? sBar[(m + 1) * LDCB + m] : 0.0f;
        headB[m] = make_float4(cb1, sb1, 0.0f, 0.0f);
    }
    for (int i = t; i < 65 * TABW; i += blockDim.x) {
        int m = i / TABW, l = i % TABW;
        if (l >= m + 2 && l <= NDEG) {
            double dl = (double)l, dm = (double)m;
            double d1 = (dl - dm) * (dl + dm);
            float v1 = (float)sqrt((2.0 * dl + 1.0) * (2.0 * dl - 1.0) / d1);
            double d2   = (dl + dm) * (dl - dm) * (2.0 * dl - 3.0);
            double num2 = (dl + dm - 1.0) * (2.0 * dl + 1.0) * (dl - dm - 1.0);
            float v2 = (float)sqrt(num2 / d2);
            tab[i] = make_float4(v1, v2, cBar[l * LDCB + m], sBar[l * LDCB + m]);
        }
    }
}

// ---------------------------------------------------------------------------
// Main kernel. NSUB=8 subs per element, zigzag columns (sub j: m = j, 15-j,
// 16+j, 31-j, 32+j, 47-j, 48+j, 63-j; 268 inner iters each). Recursion is
// rho-scaled:  q_l = rho^l * aBar[l][m],
//   q = (u*rho)*(n1*q1) - rho^2*(n2*q0)
// and mu/r is factored out to the final store. Per column, accumulate
//   sA = sum q*cBar, sB = sum q*sBar; add re*sA + im*sB at column end.
// Inner iter: 1 dwordx4 + 6 VALU.
// ---------------------------------------------------------------------------
__global__ __launch_bounds__(256) void pines_kernel(
        const float4* __restrict__ inputs,
        const float4* __restrict__ tab,
        const float4* __restrict__ headA,
        const float4* __restrict__ headB,
        float* __restrict__ out, int B) {
    __shared__ float part[NSUB][EPB];

    int t = threadIdx.x;
    int j = t >> 5;                 // sub index 0..7
    int e = t & (EPB - 1);          // element-in-block
    int elem = blockIdx.x * EPB + e;
    int lelem = elem < B ? elem : (B - 1);

    float4 in = inputs[lelem];
    float r = in.x, ss = in.y, tt = in.z, u = in.w;

    float rho  = AREF_F / r;
    float rho2 = rho * rho;
    float ur   = u * rho;

    int d1 = 15 - 2 * j;
    int d2 = 1 + 2 * j;

    auto cpow = [&](int e_, float& re_, float& im_) {
        float br = ss, bi = tt;
        re_ = 1.0f; im_ = 0.0f;
        int ee = e_;
        while (ee) {
            if (ee & 1) {
                float nr = re_ * br - im_ * bi;
                im_ = re_ * bi + im_ * br;
                re_ = nr;
            }
            float sr = br * br - bi * bi;
            bi = 2.0f * br * bi;
            br = sr;
            ee >>= 1;
        }
    };
    auto rpow = [&](int e_) {
        float b = rho, acc = 1.0f;
        int ee = e_;
        while (ee) {
            if (ee & 1) acc *= b;
            b *= b;
            ee >>= 1;
        }
        return acc;
    };

    float re, im;      cpow(j, re, im);
    float s1r, s1i;    cpow(d1, s1r, s1i);
    float s2r, s2i;    cpow(d2, s2r, s2i);
    float rstep1 = rpow(d1);
    float rstep2 = rpow(d2);
    float rho_m  = rpow(j);              // rho^m at m = j

    float sum = (j == 0) ? 1.0f : 0.0f;  // l = 0 term (times mu/r at end)

    int m = j;
    #pragma unroll 1
    for (int k = 0; k < 8; ++k) {
        float4 ha = headA[m];
        float4 hb = headB[m];
        float q0 = ha.x * rho_m;                       // q at l = m
        float sA = (m >= 1) ? q0 * ha.z : 0.0f;        // diag contribution
        float sB = (m >= 1) ? q0 * ha.w : 0.0f;
        float q1 = (ha.y * u) * (rho_m * rho);         // q at l = m+1
        sA = fmaf(q1, hb.x, sA);
        sB = fmaf(q1, hb.y, sB);

        const float4* tp = tab + (m * TABW + m + 2);
        for (int l = m + 2; l <= NDEG; ++l) {
            float4 c = *tp++;                          // n1, n2, cB, sB
            float t1 = c.x * q1;
            float t2 = ur * t1;
            float t3 = c.y * q0;
            float q  = fmaf(-rho2, t3, t2);
            sA = fmaf(q, c.z, sA);
            sB = fmaf(q, c.w, sB);
            q0 = q1;
            q1 = q;
        }
        sum = fmaf(re, sA, sum);
        sum = fmaf(im, sB, sum);

        // zigzag advance: even k -> +d1, odd k -> +d2
        if (k & 1) {
            float nr = re * s2r - im * s2i;
            im = re * s2i + im * s2r; re = nr;
            rho_m *= rstep2; m += d2;
        } else {
            float nr = re * s1r - im * s1i;
            im = re * s1i + im * s1r; re = nr;
            rho_m *= rstep1; m += d1;
        }
    }
    // sub 0 lands on m = 64: diagonal-only column
    if (j == 0) {
        float4 ha = headA[NDEG];
        float q0 = ha.x * rho_m;
        sum = fmaf(re * q0, ha.z, sum);
        sum = fmaf(im * q0, ha.w, sum);
    }

    part[j][e] = sum;
    __syncthreads();
    if (j == 0) {
        float tot = 0.0f;
        #pragma unroll
        for (int q = 0; q < NSUB; ++q) tot += part[q][e];
        if (elem < B) out[elem] = -(MU_F / r) * tot;
    }
}

extern "C" void kernel_launch(void* const* d_in, const int* in_sizes, int n_in,
                              void* d_out, int out_size, void* d_ws, size_t ws_size,
                              hipStream_t stream) {
    const float* inputs = (const float*)d_in[0];   // (B, 4)
    const float* cBar   = (const float*)d_in[1];   // (67, 67)
    const float* sBar   = (const float*)d_in[2];   // (67, 67)
    float* out = (float*)d_out;
    int B = in_sizes[0] / 4;

    float4* tab   = (float4*)d_ws;                 // 65*66 float4 = 68,640 B
    float4* headA = tab + 65 * TABW;               // 65 float4
    float4* headB = headA + 65;                    // 65 float4

    hipLaunchKernelGGL(pines_setup, dim3(1), dim3(256), 0, stream,
                       cBar, sBar, tab, headA, headB);

    int blocks = (B + EPB - 1) / EPB;
    hipLaunchKernelGGL(pines_kernel, dim3(blocks), dim3(256), 0, stream,
                       (const float4*)inputs, tab, headA, headB, out, B);
}

// Round 4
// 110.077 us; speedup vs baseline: 3.5025x; 1.2653x over previous
//
#include <hip/hip_runtime.h>
#include <math.h>

#define NDEG 64          // N
#define LMAX 66          // N + 2 (constant-table dimension)
#define LDCB 67          // cBar/sBar row stride (N + 3)
#define TABW 66          // tab row width: tab[m*TABW + l]

#define MU_F   398600441800000.0f
#define AREF_F 6378136.3f

#define NSUB 8           // sub-waves per element group
#define EPW  64          // elements per wave (= wave size)

// ---------------------------------------------------------------------------
// Setup (1 block, 256 threads), fully parallel:
//   tab[m*TABW + l] = (n1[l][m], n2[l][m], cBar[l][m], sBar[l][m]),  m+2<=l<=64
//   headA[m] = (diag[m], sub[m+1]*diag[m+1], cBar[m][m], sBar[m][m])
//   headB[m] = (cBar[m+1][m], sBar[m+1][m], 0, 0)
// diag prefix products in f64 (66 threads, each its own prefix);
// n1/n2 in fp32 — integer products < 2^24 are exact, sqrtf is 1-ulp.
// ---------------------------------------------------------------------------
__global__ void pines_setup(const float* __restrict__ cBar,
                            const float* __restrict__ sBar,
                            float4* __restrict__ tab,
                            float4* __restrict__ headA,
                            float4* __restrict__ headB) {
    __shared__ float s_diag[LMAX], s_sub[LMAX];
    int t = threadIdx.x;
    if (t < LMAX) {
        double d = 1.0;
        for (int l = 1; l <= t; ++l) {
            double kp = (l == 1) ? 1.0 : 2.0;   // k[l-1]
            d *= sqrt((2.0 * l + 1.0) * 2.0 / (2.0 * l * kp));
        }
        s_diag[t] = (float)d;
        double kp = (t == 1) ? 1.0 : 2.0;       // k[t-1]
        s_sub[t] = (t == 0) ? 0.0f : (float)sqrt(2.0 * t * kp / 2.0);
    }
    __syncthreads();
    for (int m = t; m <= NDEG; m += blockDim.x) {
        float dg = s_diag[m];
        float sd = s_sub[m + 1] * s_diag[m + 1];          // m+1 <= 65
        headA[m] = make_float4(dg, sd, cBar[m * LDCB + m], sBar[m * LDCB + m]);
        float cb1 = (m < NDEG) ? cBar[(m + 1) * LDCB + m] : 0.0f;
        float sb1 = (m < NDEG) ? sBar[(m + 1) * LDCB + m] : 0.0f;
        headB[m] = make_float4(cb1, sb1, 0.0f, 0.0f);
    }
    for (int i = t; i < 65 * TABW; i += blockDim.x) {
        int m = i / TABW, l = i % TABW;
        if (l >= m + 2 && l <= NDEG) {
            // all integer products below are < 2^24 -> exact in fp32
            float d1f = (float)((l - m) * (l + m));
            float v1  = sqrtf((float)((2 * l + 1) * (2 * l - 1)) / d1f);
            float d2f = (float)((l + m) * (l - m) * (2 * l - 3));
            float n2f = (float)((l + m - 1) * (2 * l + 1) * (l - m - 1));
            float v2  = sqrtf(n2f / d2f);
            tab[i] = make_float4(v1, v2, cBar[l * LDCB + m], sBar[l * LDCB + m]);
        }
    }
}

// ---------------------------------------------------------------------------
// Main kernel. Block = 512 threads = 8 waves; wave w = sub index j = w,
// lanes = 64 distinct elements. All table indices (m, l) are WAVE-UNIFORM:
// forced into SGPRs via readfirstlane so table reads become s_load on the
// scalar pipe (co-issues with VALU, no VGPR addr math, no vmcnt in the
// VALU stream). Zigzag column split: sub j owns m = j, 15-j, 16+j, 31-j,
// 32+j, 47-j, 48+j, 63-j (268 inner iters each, perfectly balanced).
// Recursion rho-scaled: q_l = rho^l*aBar[l][m];
//   q = (u*rho)*(n1*q1) - rho^2*(n2*q0); mu/r factored to the store.
// ---------------------------------------------------------------------------
__global__ __launch_bounds__(512) void pines_kernel(
        const float4* __restrict__ inputs,
        const float4* __restrict__ tab,
        const float4* __restrict__ headA,
        const float4* __restrict__ headB,
        float* __restrict__ out, int B) {
    __shared__ float part[NSUB][EPW];

    int t = threadIdx.x;
    int j = __builtin_amdgcn_readfirstlane(t >> 6);   // wave index = sub index
    int e = t & (EPW - 1);                            // lane = element-in-group
    int elem = blockIdx.x * EPW + e;
    int lelem = elem < B ? elem : (B - 1);

    float4 in = inputs[lelem];
    float r = in.x, ss = in.y, tt = in.z, u = in.w;

    float rho  = AREF_F / r;
    float rho2 = rho * rho;
    float ur   = u * rho;

    int d1 = 15 - 2 * j;
    int d2 = 1 + 2 * j;

    auto cpow = [&](int e_, float& re_, float& im_) {
        float br = ss, bi = tt;
        re_ = 1.0f; im_ = 0.0f;
        int ee = e_;
        while (ee) {
            if (ee & 1) {
                float nr = re_ * br - im_ * bi;
                im_ = re_ * bi + im_ * br;
                re_ = nr;
            }
            float sr = br * br - bi * bi;
            bi = 2.0f * br * bi;
            br = sr;
            ee >>= 1;
        }
    };
    auto rpow = [&](int e_) {
        float b = rho, acc = 1.0f;
        int ee = e_;
        while (ee) {
            if (ee & 1) acc *= b;
            b *= b;
            ee >>= 1;
        }
        return acc;
    };

    float re, im;      cpow(j, re, im);
    float s1r, s1i;    cpow(d1, s1r, s1i);
    float s2r, s2i;    cpow(d2, s2r, s2i);
    float rstep1 = rpow(d1);
    float rstep2 = rpow(d2);
    float rho_m  = rpow(j);              // rho^m at m = j

    float sum = (j == 0) ? 1.0f : 0.0f;  // l = 0 term (times mu/r at end)

    int m = j;                           // wave-uniform (kept scalar below)
    #pragma unroll 1
    for (int k = 0; k < 8; ++k) {
        int sm = __builtin_amdgcn_readfirstlane(m);
        float4 ha = headA[sm];
        float4 hb = headB[sm];
        float q0 = ha.x * rho_m;                       // q at l = m
        float sA = (sm >= 1) ? q0 * ha.z : 0.0f;       // diag contribution
        float sB = (sm >= 1) ? q0 * ha.w : 0.0f;
        float q1 = (ha.y * u) * (rho_m * rho);         // q at l = m+1
        sA = fmaf(q1, hb.x, sA);
        sB = fmaf(q1, hb.y, sB);

        const float4* __restrict__ tp = tab + sm * TABW;
        for (int l = sm + 2; l <= NDEG; ++l) {
            float4 c = tp[l];                          // n1, n2, cB, sB (s_load)
            float t1 = c.x * q1;
            float t2 = ur * t1;
            float t3 = c.y * q0;
            float q  = fmaf(-rho2, t3, t2);
            sA = fmaf(q, c.z, sA);
            sB = fmaf(q, c.w, sB);
            q0 = q1;
            q1 = q;
        }
        sum = fmaf(re, sA, sum);
        sum = fmaf(im, sB, sum);

        // zigzag advance: even k -> +d1, odd k -> +d2
        if (k & 1) {
            float nr = re * s2r - im * s2i;
            im = re * s2i + im * s2r; re = nr;
            rho_m *= rstep2; m += d2;
        } else {
            float nr = re * s1r - im * s1i;
            im = re * s1i + im * s1r; re = nr;
            rho_m *= rstep1; m += d1;
        }
    }
    // sub 0 lands on m = 64: diagonal-only column
    if (j == 0) {
        float4 ha = headA[NDEG];
        float q0 = ha.x * rho_m;
        sum = fmaf(re * q0, ha.z, sum);
        sum = fmaf(im * q0, ha.w, sum);
    }

    part[j][e] = sum;
    __syncthreads();
    if (j == 0) {
        float tot = 0.0f;
        #pragma unroll
        for (int q = 0; q < NSUB; ++q) tot += part[q][e];
        if (elem < B) out[elem] = -(MU_F / r) * tot;
    }
}

extern "C" void kernel_launch(void* const* d_in, const int* in_sizes, int n_in,
                              void* d_out, int out_size, void* d_ws, size_t ws_size,
                              hipStream_t stream) {
    const float* inputs = (const float*)d_in[0];   // (B, 4)
    const float* cBar   = (const float*)d_in[1];   // (67, 67)
    const float* sBar   = (const float*)d_in[2];   // (67, 67)
    float* out = (float*)d_out;
    int B = in_sizes[0] / 4;

    float4* tab   = (float4*)d_ws;                 // 65*66 float4 = 68,640 B
    float4* headA = tab + 65 * TABW;               // 65 float4
    float4* headB = headA + 65;                    // 65 float4

    hipLaunchKernelGGL(pines_setup, dim3(1), dim3(256), 0, stream,
                       cBar, sBar, tab, headA, headB);

    int blocks = (B + EPW - 1) / EPW;
    hipLaunchKernelGGL(pines_kernel, dim3(blocks), dim3(512), 0, stream,
                       (const float4*)inputs, tab, headA, headB, out, B);
}

// Round 5
// 106.827 us; speedup vs baseline: 3.6091x; 1.0304x over previous
//
#include <hip/hip_runtime.h>
#include <math.h>

#define NDEG 64          // N
#define LMAX 66          // N + 2
#define LDCB 67          // cBar/sBar row stride (N + 3)
#define NCOL 63          // columns m=0..62 have inner (l>=m+2) entries

#define MU_F   398600441800000.0f
#define AREF_F 6378136.3f

#define NSUB 8           // sub-waves per element group
#define EPW  64          // elements per wave (= wave size)

// 64-byte group of 4 packed constant entries (n1,n2,cBar,sBar)
struct Cons4 { float4 v[4]; };

// ---------------------------------------------------------------------------
// Setup (1 block). Packed padded triangle:
//   column m (m=0..62): entries for l = m+2..64 (count 63-m), padded with
//   zeros to a multiple of 4 entries (64 B) so the main loop can consume
//   whole Cons4 groups. colstart[m] = first float4 index of column m.
// Heads: headA[m] = (diag[m], sub[m+1]*diag[m+1], cBar[m][m], sBar[m][m])
//        headB[m] = (cBar[m+1][m], sBar[m+1][m], 0, 0)
// ---------------------------------------------------------------------------
__global__ void pines_setup(const float* __restrict__ cBar,
                            const float* __restrict__ sBar,
                            float4* __restrict__ tab,
                            float4* __restrict__ headA,
                            float4* __restrict__ headB,
                            int*    __restrict__ colstart) {
    __shared__ float s_diag[LMAX], s_sub[LMAX];
    int t = threadIdx.x;
    if (t < LMAX) {
        double d = 1.0;
        for (int l = 1; l <= t; ++l) {
            double kp = (l == 1) ? 1.0 : 2.0;   // k[l-1]
            d *= sqrt((2.0 * l + 1.0) * 2.0 / (2.0 * l * kp));
        }
        s_diag[t] = (float)d;
        double kp = (t == 1) ? 1.0 : 2.0;
        s_sub[t] = (t == 0) ? 0.0f : (float)sqrt(2.0 * t * kp / 2.0);
    }
    __syncthreads();
    if (t <= NDEG) {
        int m = t;
        headA[m] = make_float4(s_diag[m], s_sub[m + 1] * s_diag[m + 1],
                               cBar[m * LDCB + m], sBar[m * LDCB + m]);
        float cb1 = (m < NDEG) ? cBar[(m + 1) * LDCB + m] : 0.0f;
        float sb1 = (m < NDEG) ? sBar[(m + 1) * LDCB + m] : 0.0f;
        headB[m] = make_float4(cb1, sb1, 0.0f, 0.0f);

        // column start: prefix of padded lengths (<=64 adds, trivial)
        int off = 0;
        for (int mm = 0; mm < m && mm < NCOL; ++mm)
            off += ((63 - mm + 3) >> 2) << 2;
        colstart[m] = off;

        if (m < NCOL) {
            int cnt = 63 - m;
            int pad = ((cnt + 3) >> 2) << 2;
            for (int i = 0; i < pad; ++i) {
                float4 v = make_float4(0.0f, 0.0f, 0.0f, 0.0f);
                if (i < cnt) {
                    int l = m + 2 + i;
                    // integer products < 2^24 -> exact in fp32
                    float d1f = (float)((l - m) * (l + m));
                    float v1  = sqrtf((float)((2 * l + 1) * (2 * l - 1)) / d1f);
                    float d2f = (float)((l + m) * (l - m) * (2 * l - 3));
                    float n2f = (float)((l + m - 1) * (2 * l + 1) * (l - m - 1));
                    float v2  = sqrtf(n2f / d2f);
                    v = make_float4(v1, v2, cBar[l * LDCB + m], sBar[l * LDCB + m]);
                }
                tab[off + i] = v;
            }
        }
    }
}

// ---------------------------------------------------------------------------
// Main kernel. Block = 512 = 8 waves; wave w = sub index j, lanes = 64
// elements. Table indices wave-uniform (readfirstlane) -> s_load on the
// scalar pipe; inner loop consumes one 64 B Cons4 group per 4 iterations
// (4x fewer SMEM requests, natural prefetch distance). Zigzag columns:
// sub j owns m = j, 15-j, 16+j, 31-j, 32+j, 47-j, 48+j, 63-j; every sub
// gets exactly 64 groups -> perfect balance. Recursion rho-scaled:
//   q_l = rho^l*aBar[l][m];  q = (u*rho)*(n1*q1) - rho^2*(n2*q0)
// mu/r factored into the final store. Zero-pad entries are inert (q=0,
// cB=sB=0) and the recursion state is discarded at column end.
// ---------------------------------------------------------------------------
__global__ __launch_bounds__(512) void pines_kernel(
        const float4* __restrict__ inputs,
        const float4* __restrict__ tab,
        const float4* __restrict__ headA,
        const float4* __restrict__ headB,
        const int*    __restrict__ colstart,
        float* __restrict__ out, int B) {
    __shared__ float part[NSUB][EPW];

    int t = threadIdx.x;
    int j = __builtin_amdgcn_readfirstlane(t >> 6);
    int e = t & (EPW - 1);
    int elem = blockIdx.x * EPW + e;
    int lelem = elem < B ? elem : (B - 1);

    float4 in = inputs[lelem];
    float r = in.x, ss = in.y, tt = in.z, u = in.w;

    float rho  = AREF_F / r;
    float rho2 = rho * rho;
    float ur   = u * rho;

    int d1 = 15 - 2 * j;
    int d2 = 1 + 2 * j;

    auto cpow = [&](int e_, float& re_, float& im_) {
        float br = ss, bi = tt;
        re_ = 1.0f; im_ = 0.0f;
        int ee = e_;
        while (ee) {
            if (ee & 1) {
                float nr = re_ * br - im_ * bi;
                im_ = re_ * bi + im_ * br;
                re_ = nr;
            }
            float sr = br * br - bi * bi;
            bi = 2.0f * br * bi;
            br = sr;
            ee >>= 1;
        }
    };
    auto rpow = [&](int e_) {
        float b = rho, acc = 1.0f;
        int ee = e_;
        while (ee) {
            if (ee & 1) acc *= b;
            b *= b;
            ee >>= 1;
        }
        return acc;
    };

    float re, im;      cpow(j, re, im);
    float s1r, s1i;    cpow(d1, s1r, s1i);
    float s2r, s2i;    cpow(d2, s2r, s2i);
    float rstep1 = rpow(d1);
    float rstep2 = rpow(d2);
    float rho_m  = rpow(j);              // rho^m at m = j

    float sum = (j == 0) ? 1.0f : 0.0f;  // l = 0 term (times mu/r at end)

    int m = j;                           // wave-uniform
    #pragma unroll 1
    for (int k = 0; k < 8; ++k) {
        int sm = __builtin_amdgcn_readfirstlane(m);
        float4 ha = headA[sm];
        float4 hb = headB[sm];
        float q0 = ha.x * rho_m;                       // q at l = m
        float sA = (sm >= 1) ? q0 * ha.z : 0.0f;
        float sB = (sm >= 1) ? q0 * ha.w : 0.0f;
        float q1 = (ha.y * u) * (rho_m * rho);         // q at l = m+1
        sA = fmaf(q1, hb.x, sA);
        sB = fmaf(q1, hb.y, sB);

        int scol = __builtin_amdgcn_readfirstlane(colstart[sm]);
        int ng   = __builtin_amdgcn_readfirstlane((63 - sm + 3) >> 2);
        const Cons4* __restrict__ gp = (const Cons4*)(tab + scol);
        #pragma unroll 1
        for (int g = 0; g < ng; ++g) {
            Cons4 c = gp[g];                           // 64 B scalar load
            #pragma unroll
            for (int q4 = 0; q4 < 4; ++q4) {
                float4 cc = c.v[q4];
                float t1 = cc.x * q1;
                float t2 = ur * t1;
                float t3 = cc.y * q0;
                float q  = fmaf(-rho2, t3, t2);
                sA = fmaf(q, cc.z, sA);
                sB = fmaf(q, cc.w, sB);
                q0 = q1;
                q1 = q;
            }
        }
        sum = fmaf(re, sA, sum);
        sum = fmaf(im, sB, sum);

        // zigzag advance: even k -> +d1, odd k -> +d2
        if (k & 1) {
            float nr = re * s2r - im * s2i;
            im = re * s2i + im * s2r; re = nr;
            rho_m *= rstep2; m += d2;
        } else {
            float nr = re * s1r - im * s1i;
            im = re * s1i + im * s1r; re = nr;
            rho_m *= rstep1; m += d1;
        }
    }
    // sub 0 lands on m = 64: diagonal-only column
    if (j == 0) {
        float4 ha = headA[NDEG];
        float q0 = ha.x * rho_m;
        sum = fmaf(re * q0, ha.z, sum);
        sum = fmaf(im * q0, ha.w, sum);
    }

    part[j][e] = sum;
    __syncthreads();
    if (j == 0) {
        float tot = 0.0f;
        #pragma unroll
        for (int q = 0; q < NSUB; ++q) tot += part[q][e];
        if (elem < B) out[elem] = -(MU_F / r) * tot;
    }
}

extern "C" void kernel_launch(void* const* d_in, const int* in_sizes, int n_in,
                              void* d_out, int out_size, void* d_ws, size_t ws_size,
                              hipStream_t stream) {
    const float* inputs = (const float*)d_in[0];   // (B, 4)
    const float* cBar   = (const float*)d_in[1];   // (67, 67)
    const float* sBar   = (const float*)d_in[2];   // (67, 67)
    float* out = (float*)d_out;
    int B = in_sizes[0] / 4;

    // packed padded triangle: sum_m ceil((63-m)/4)*4 <= 63*64 = 4032 float4
    float4* tab   = (float4*)d_ws;                 // <= 64,512 B
    float4* headA = tab + 4032;                    // 65 float4
    float4* headB = headA + 65;
    int*    colst = (int*)(headB + 65);            // 65 ints

    hipLaunchKernelGGL(pines_setup, dim3(1), dim3(128), 0, stream,
                       cBar, sBar, tab, headA, headB, colst);

    int blocks = (B + EPW - 1) / EPW;
    hipLaunchKernelGGL(pines_kernel, dim3(blocks), dim3(512), 0, stream,
                       (const float4*)inputs, tab, headA, headB, colst,
                       out, B);
}

// Round 6
// 90.336 us; speedup vs baseline: 4.2679x; 1.1826x over previous
//
#include <hip/hip_runtime.h>
#include <math.h>

#define NDEG 64          // N
#define LMAX 66          // N + 2
#define LDCB 67          // cBar/sBar row stride (N + 3)
#define NCOL 63          // columns m=0..62 have inner (l>=m+2) entries
#define TAB_F4 2112      // total packed float4 count = sum_m 4*ceil((63-m)/4)

#define MU_F   398600441800000.0f
#define AREF_F 6378136.3f

#define NSUB 8           // sub-waves per element group
#define EPW  64          // elements per wave (= wave size)

// 64-byte group of 4 packed constant entries (n1,n2,cBar,sBar)
struct Cons4 { float4 v[4]; };

// ---------------------------------------------------------------------------
// Setup, fully parallel: grid = 17 blocks x 256.
//  block 0, thread m (m<=64): heads + colstart
//    headA[m] = (diag[m], sub[m+1]*diag[m+1], cBar[m][m], sBar[m][m])
//    headB[m] = (cBar[m+1][m], sBar[m+1][m], 0, 0)
//    colstart[m] = packed float4 offset of column m
//  blocks 1..16, one thread per (m,i) in the 63x64 rectangle: one packed
//    triangle entry tab[colstart(m)+i] = (n1,n2,cB,sB) (zero if i>=cnt pad).
//  Integer products < 2^24 are exact in fp32; sqrtf is 1-ulp.
// ---------------------------------------------------------------------------
__global__ void pines_setup(const float* __restrict__ cBar,
                            const float* __restrict__ sBar,
                            float4* __restrict__ tab,
                            float4* __restrict__ headA,
                            float4* __restrict__ headB,
                            int*    __restrict__ colstart) {
    int t = threadIdx.x;
    if (blockIdx.x == 0) {
        if (t <= NDEG) {
            int m = t;
            // diag[m] prefix in f64: f(l) = sqrt((2l+1)*2 / (2l*k[l-1]))
            double d = 1.0;
            for (int l = 1; l <= m; ++l) {
                double kp = (l == 1) ? 1.0 : 2.0;
                d *= sqrt((2.0 * l + 1.0) * 2.0 / (2.0 * l * kp));
            }
            double fnext;
            {
                int l = m + 1;
                double kp = (l == 1) ? 1.0 : 2.0;
                fnext = sqrt((2.0 * l + 1.0) * 2.0 / (2.0 * l * kp));
            }
            double diag1 = d * fnext;                         // diag[m+1]
            double sub1  = sqrt((double)(m + 1) * ((m == 0) ? 1.0 : 2.0)); // sub[m+1]
            headA[m] = make_float4((float)d, (float)(sub1 * diag1),
                                   cBar[m * LDCB + m], sBar[m * LDCB + m]);
            float cb1 = (m < NDEG) ? cBar[(m + 1) * LDCB + m] : 0.0f;
            float sb1 = (m < NDEG) ? sBar[(m + 1) * LDCB + m] : 0.0f;
            headB[m] = make_float4(cb1, sb1, 0.0f, 0.0f);
            int off = 0;
            for (int mm = 0; mm < m && mm < NCOL; ++mm)
                off += ((63 - mm + 3) >> 2) << 2;
            colstart[m] = off;                                // m>=63 -> TAB_F4
        }
    } else {
        int idx = (blockIdx.x - 1) * blockDim.x + t;          // 0..4095
        if (idx < NCOL * 64) {
            int m = idx >> 6, i = idx & 63;
            int cnt = 63 - m;
            int pad = ((cnt + 3) >> 2) << 2;
            if (i < pad) {
                int off = 0;
                for (int mm = 0; mm < m; ++mm)
                    off += ((63 - mm + 3) >> 2) << 2;
                float4 v = make_float4(0.0f, 0.0f, 0.0f, 0.0f);
                if (i < cnt) {
                    int l = m + 2 + i;
                    float d1f = (float)((l - m) * (l + m));
                    float v1  = sqrtf((float)((2 * l + 1) * (2 * l - 1)) / d1f);
                    float d2f = (float)((l + m) * (l - m) * (2 * l - 3));
                    float n2f = (float)((l + m - 1) * (2 * l + 1) * (l - m - 1));
                    float v2  = sqrtf(n2f / d2f);
                    v = make_float4(v1, v2, cBar[l * LDCB + m], sBar[l * LDCB + m]);
                }
                tab[off + i] = v;
            }
        }
    }
}

// ---------------------------------------------------------------------------
// Main kernel. Block = 512 = 8 waves; wave w = sub index j, lanes = 64
// elements. Table reads are wave-uniform -> s_load on the scalar pipe.
// Software-pipelined at two levels: (a) next 64 B Cons4 group prefetched
// while the current one is processed; (b) next column's heads + colstart
// prefetched during the current column's group loop. Prefetch indices
// clamped to 64; overruns read adjacent ws, values never consumed (and the
// post-loop ha holds headA[64], exactly what the j==0 tail needs).
// Zigzag: sub j owns m = j,15-j,16+j,31-j,32+j,47-j,48+j,63-j; 64 padded
// groups each -> perfect balance. Recursion rho-scaled:
//   q_l = rho^l*aBar[l][m];  q = (u*rho)*(n1*q1) - rho^2*(n2*q0)
// mu/r factored into the final store; zero-pad entries are inert.
// ---------------------------------------------------------------------------
__global__ __launch_bounds__(512) void pines_kernel(
        const float4* __restrict__ inputs,
        const float4* __restrict__ tab,
        const float4* __restrict__ headA,
        const float4* __restrict__ headB,
        const int*    __restrict__ colstart,
        float* __restrict__ out, int B) {
    __shared__ float part[NSUB][EPW];

    int t = threadIdx.x;
    int j = __builtin_amdgcn_readfirstlane(t >> 6);
    int e = t & (EPW - 1);
    int elem = blockIdx.x * EPW + e;
    int lelem = elem < B ? elem : (B - 1);

    float4 in = inputs[lelem];
    float r = in.x, ss = in.y, tt = in.z, u = in.w;

    float rho  = AREF_F / r;
    float rho2 = rho * rho;
    float ur   = u * rho;

    int d1 = 15 - 2 * j;
    int d2 = 1 + 2 * j;

    auto cpow = [&](int e_, float& re_, float& im_) {
        float br = ss, bi = tt;
        re_ = 1.0f; im_ = 0.0f;
        int ee = e_;
        while (ee) {
            if (ee & 1) {
                float nr = re_ * br - im_ * bi;
                im_ = re_ * bi + im_ * br;
                re_ = nr;
            }
            float sr = br * br - bi * bi;
            bi = 2.0f * br * bi;
            br = sr;
            ee >>= 1;
        }
    };
    auto rpow = [&](int e_) {
        float b = rho, acc = 1.0f;
        int ee = e_;
        while (ee) {
            if (ee & 1) acc *= b;
            b *= b;
            ee >>= 1;
        }
        return acc;
    };

    float re, im;      cpow(j, re, im);
    float s1r, s1i;    cpow(d1, s1r, s1i);
    float s2r, s2i;    cpow(d2, s2r, s2i);
    float rstep1 = rpow(d1);
    float rstep2 = rpow(d2);
    float rho_m  = rpow(j);              // rho^m at m = j

    float sum = (j == 0) ? 1.0f : 0.0f;  // l = 0 term (times mu/r at end)

    // zigzag m-sequence (wave-uniform)
    int ms[9];
    ms[0] = j;
    #pragma unroll
    for (int k = 0; k < 8; ++k) ms[k + 1] = ms[k] + ((k & 1) ? d2 : d1);
    // ms[8] = j + 64 (== 64 for j == 0)

    int sm = __builtin_amdgcn_readfirstlane(ms[0]);
    float4 ha = headA[sm];
    float4 hb = headB[sm];
    int scol  = __builtin_amdgcn_readfirstlane(colstart[sm]);

    #pragma unroll 1
    for (int k = 0; k < 8; ++k) {
        // prefetch next column's heads + start (clamped; harmless overrun)
        int smn = ms[k + 1] > 64 ? 64 : ms[k + 1];
        smn = __builtin_amdgcn_readfirstlane(smn);
        float4 ha_n = headA[smn];
        float4 hb_n = headB[smn];
        int scol_n  = __builtin_amdgcn_readfirstlane(colstart[smn]);

        float q0 = ha.x * rho_m;                       // q at l = m
        float sA = (sm >= 1) ? q0 * ha.z : 0.0f;
        float sB = (sm >= 1) ? q0 * ha.w : 0.0f;
        float q1 = (ha.y * u) * (rho_m * rho);         // q at l = m+1
        sA = fmaf(q1, hb.x, sA);
        sB = fmaf(q1, hb.y, sB);

        int ng = __builtin_amdgcn_readfirstlane((63 - sm + 3) >> 2);
        const Cons4* __restrict__ gp = (const Cons4*)(tab + scol);
        Cons4 cur = gp[0];
        #pragma unroll 1
        for (int g = 0; g < ng; ++g) {
            Cons4 nxt = gp[g + 1];                     // prefetch (may overrun
                                                       //  by 64 B into ws; unused)
            #pragma unroll
            for (int q4 = 0; q4 < 4; ++q4) {
                float4 cc = cur.v[q4];
                float t1 = cc.x * q1;
                float t2 = ur * t1;
                float t3 = cc.y * q0;
                float q  = fmaf(-rho2, t3, t2);
                sA = fmaf(q, cc.z, sA);
                sB = fmaf(q, cc.w, sB);
                q0 = q1;
                q1 = q;
            }
            cur = nxt;
        }
        sum = fmaf(re, sA, sum);
        sum = fmaf(im, sB, sum);

        // zigzag advance: even k -> +d1, odd k -> +d2
        if (k & 1) {
            float nr = re * s2r - im * s2i;
            im = re * s2i + im * s2r; re = nr;
            rho_m *= rstep2;
        } else {
            float nr = re * s1r - im * s1i;
            im = re * s1i + im * s1r; re = nr;
            rho_m *= rstep1;
        }
        sm = smn; ha = ha_n; hb = hb_n; scol = scol_n;
    }
    // sub 0 lands on m = 64: diagonal-only column (ha == headA[64] here)
    if (j == 0) {
        float q0 = ha.x * rho_m;
        sum = fmaf(re * q0, ha.z, sum);
        sum = fmaf(im * q0, ha.w, sum);
    }

    part[j][e] = sum;
    __syncthreads();
    if (j == 0) {
        float tot = 0.0f;
        #pragma unroll
        for (int q = 0; q < NSUB; ++q) tot += part[q][e];
        if (elem < B) out[elem] = -(MU_F / r) * tot;
    }
}

extern "C" void kernel_launch(void* const* d_in, const int* in_sizes, int n_in,
                              void* d_out, int out_size, void* d_ws, size_t ws_size,
                              hipStream_t stream) {
    const float* inputs = (const float*)d_in[0];   // (B, 4)
    const float* cBar   = (const float*)d_in[1];   // (67, 67)
    const float* sBar   = (const float*)d_in[2];   // (67, 67)
    float* out = (float*)d_out;
    int B = in_sizes[0] / 4;

    float4* tab   = (float4*)d_ws;                 // TAB_F4 float4 = 33,792 B
    float4* headA = tab + TAB_F4;                  // 65 float4
    float4* headB = headA + 65;
    int*    colst = (int*)(headB + 65);            // 65 ints

    hipLaunchKernelGGL(pines_setup, dim3(17), dim3(256), 0, stream,
                       cBar, sBar, tab, headA, headB, colst);

    int blocks = (B + EPW - 1) / EPW;
    hipLaunchKernelGGL(pines_kernel, dim3(blocks), dim3(512), 0, stream,
                       (const float4*)inputs, tab, headA, headB, colst,
                       out, B);
}